// Round 1
// baseline (84558.966 us; speedup 1.0000x reference)
//
#include <hip/hip_runtime.h>
#include <cstdint>
#include <cstddef>

#define TT 8192
#define DD 512
#define MM 2048   // M1 == M2
#define KK 1024
#define SCAN_WGS 256

// ---------- coherent (L3 / coherence-point) memory helpers ----------
// sc0 sc1 bypasses L1+L2 on gfx950 -> reads/writes meet at the memory-side L3,
// which is the only cache level coherent across XCDs.
__device__ __forceinline__ int coh_load_i32(const int* p) {
  int v;
  asm volatile("global_load_dword %0, %1, off sc0 sc1\n\t"
               "s_waitcnt vmcnt(0)"
               : "=v"(v) : "v"(p) : "memory");
  return v;
}
__device__ __forceinline__ void coh_store_i32(int* p, int v) {
  asm volatile("global_store_dword %0, %1, off sc0 sc1" :: "v"(p), "v"(v) : "memory");
}
__device__ __forceinline__ void coh_load_f8(const float* p, float4& a, float4& b) {
  asm volatile("global_load_dwordx4 %0, %2, off sc0 sc1\n\t"
               "global_load_dwordx4 %1, %2, off offset:16 sc0 sc1\n\t"
               "s_waitcnt vmcnt(0)"
               : "=v"(a), "=v"(b) : "v"(p) : "memory");
}
__device__ __forceinline__ void coh_store_f32(float* p, float v) {
  asm volatile("global_store_dword %0, %1, off sc0 sc1" :: "v"(p), "v"(v) : "memory");
}

// ---------- fp32 tiled GEMM: C[M,N] = A[M,K] @ B[K,N] + bias[N] ----------
// 128x128 tile, BK=16, 256 threads, 8x8 micro-tile per thread.
// A staged transposed in LDS (broadcast reads), B column-split in 4-float
// granules (tx*4 and 64+tx*4) to keep ds_read_b128 at <=2-way bank aliasing.
__global__ void __launch_bounds__(256) gemm_bias_f32(
    const float* __restrict__ A, const float* __restrict__ B,
    const float* __restrict__ bias, float* __restrict__ C,
    int M, int N, int K)
{
  __shared__ float As[16][128];   // As[k][m]
  __shared__ float Bs[16][128];   // Bs[k][n]
  const int tid = threadIdx.x;
  const int tx = tid & 15, ty = tid >> 4;
  const int row0 = blockIdx.y * 128, col0 = blockIdx.x * 128;
  const int arow = tid >> 1;          // 0..127
  const int ak0  = (tid & 1) * 8;     // 0 or 8
  const int brow = tid >> 4;          // 0..15
  const int bcol = (tid & 15) * 8;

  const float* Aptr = A + (size_t)(row0 + arow) * K + ak0;
  const float* Bptr = B + (size_t)brow * N + col0 + bcol;

  float acc[8][8];
  #pragma unroll
  for (int i = 0; i < 8; ++i)
    #pragma unroll
    for (int j = 0; j < 8; ++j) acc[i][j] = 0.f;

  for (int kk = 0; kk < K; kk += 16) {
    float4 a0 = *(const float4*)(Aptr + kk);
    float4 a1 = *(const float4*)(Aptr + kk + 4);
    float4 b0 = *(const float4*)(Bptr + (size_t)kk * N);
    float4 b1 = *(const float4*)(Bptr + (size_t)kk * N + 4);
    __syncthreads();
    As[ak0+0][arow] = a0.x; As[ak0+1][arow] = a0.y;
    As[ak0+2][arow] = a0.z; As[ak0+3][arow] = a0.w;
    As[ak0+4][arow] = a1.x; As[ak0+5][arow] = a1.y;
    As[ak0+6][arow] = a1.z; As[ak0+7][arow] = a1.w;
    *(float4*)&Bs[brow][bcol]     = b0;
    *(float4*)&Bs[brow][bcol + 4] = b1;
    __syncthreads();
    #pragma unroll
    for (int k = 0; k < 16; ++k) {
      float4 av0 = *(float4*)&As[k][ty*8];
      float4 av1 = *(float4*)&As[k][ty*8 + 4];
      float4 bv0 = *(float4*)&Bs[k][tx*4];
      float4 bv1 = *(float4*)&Bs[k][64 + tx*4];
      float ar[8] = {av0.x,av0.y,av0.z,av0.w,av1.x,av1.y,av1.z,av1.w};
      float br[8] = {bv0.x,bv0.y,bv0.z,bv0.w,bv1.x,bv1.y,bv1.z,bv1.w};
      #pragma unroll
      for (int i = 0; i < 8; ++i)
        #pragma unroll
        for (int j = 0; j < 8; ++j)
          acc[i][j] += ar[i] * br[j];
    }
  }

  float4 bi0 = *(const float4*)&bias[col0 + tx*4];
  float4 bi1 = *(const float4*)&bias[col0 + 64 + tx*4];
  #pragma unroll
  for (int i = 0; i < 8; ++i) {
    size_t r = (size_t)(row0 + ty*8 + i) * N;
    float4 o0 = make_float4(acc[i][0]+bi0.x, acc[i][1]+bi0.y, acc[i][2]+bi0.z, acc[i][3]+bi0.w);
    float4 o1 = make_float4(acc[i][4]+bi1.x, acc[i][5]+bi1.y, acc[i][6]+bi1.z, acc[i][7]+bi1.w);
    *(float4*)&C[r + col0 + tx*4]      = o0;
    *(float4*)&C[r + col0 + 64 + tx*4] = o1;
  }
}

// ---------- persistent RNN scan: HX[t] = relu(HX[t] + h_{t-1} @ Wh), in place ----------
// 256 WGs x 256 threads. WG w owns output columns [8w, 8w+8).
// Wh column slice lives in REGISTERS (64 VGPR/thread), h broadcast via L3
// coherent loads, per-WG flag[w] = last completed step (init -1 by memset).
// Thread tid gates its h-slice load on flag[tid] only (point-to-point sync).
__global__ void __launch_bounds__(256) rnn_scan_f32(
    float* __restrict__ HX, const float* __restrict__ Wh,
    const float* __restrict__ h0, int* __restrict__ flags)
{
  __shared__ float h_s[MM];
  const int tid  = threadIdx.x;
  const int wg   = blockIdx.x;
  const int lane = tid & 63;
  const int wv   = tid >> 6;            // wave 0..3, owns cols wv*2, wv*2+1
  const int c0   = wg * 8 + wv * 2;     // global column of s0 (s1 = c0+1)

  // Preload weight slice into registers:
  //   w0[i],w1[i] hold Wh[k][c0], Wh[k][c0+1] for k = lane*4 + 256*i + {0..3}
  float4 w0[8], w1[8];
  #pragma unroll
  for (int i = 0; i < 8; ++i) {
    const int kb = lane*4 + 256*i;
    float2 e0 = *(const float2*)&Wh[(size_t)(kb+0)*MM + c0];
    float2 e1 = *(const float2*)&Wh[(size_t)(kb+1)*MM + c0];
    float2 e2 = *(const float2*)&Wh[(size_t)(kb+2)*MM + c0];
    float2 e3 = *(const float2*)&Wh[(size_t)(kb+3)*MM + c0];
    w0[i] = make_float4(e0.x, e1.x, e2.x, e3.x);
    w1[i] = make_float4(e0.y, e1.y, e2.y, e3.y);
  }

  for (int t = 0; t < TT; ++t) {
    // ---- gather h_{t-1} into LDS (8 floats per thread = producer tid's slice)
    float4 ha, hb;
    if (t == 0) {
      ha = ((const float4*)h0)[tid*2];
      hb = ((const float4*)h0)[tid*2 + 1];
    } else {
      while (coh_load_i32(&flags[tid]) < t - 1) {}
      coh_load_f8(HX + (size_t)(t-1)*MM + tid*8, ha, hb);
    }
    ((float4*)h_s)[tid*2]     = ha;
    ((float4*)h_s)[tid*2 + 1] = hb;
    __syncthreads();

    // prefetch x_t for my columns (regular cached load; row t untouched until now)
    float xv = 0.f;
    if (lane < 2) xv = HX[(size_t)t*MM + c0 + lane];

    // ---- dot products over k, weights register-resident
    float s0 = 0.f, s1 = 0.f;
    #pragma unroll
    for (int i = 0; i < 8; ++i) {
      float4 h4 = *(float4*)&h_s[lane*4 + 256*i];
      s0 += h4.x*w0[i].x + h4.y*w0[i].y + h4.z*w0[i].z + h4.w*w0[i].w;
      s1 += h4.x*w1[i].x + h4.y*w1[i].y + h4.z*w1[i].z + h4.w*w1[i].w;
    }
    #pragma unroll
    for (int off = 32; off; off >>= 1) {
      s0 += __shfl_xor(s0, off);
      s1 += __shfl_xor(s1, off);
    }
    if (lane < 2) {
      float s = (lane == 0) ? s0 : s1;
      float y = fmaxf(xv + s, 0.f);
      coh_store_f32(&HX[(size_t)t*MM + c0 + lane], y);
    }

    // ---- publish: drain stores (all waves), barrier, then post flag
    asm volatile("s_waitcnt vmcnt(0)" ::: "memory");
    __syncthreads();
    if (tid == 0) coh_store_i32(&flags[wg], t);
  }
}

extern "C" void kernel_launch(void* const* d_in, const int* in_sizes, int n_in,
                              void* d_out, int out_size, void* d_ws, size_t ws_size,
                              hipStream_t stream) {
  (void)in_sizes; (void)n_in; (void)out_size; (void)ws_size;

  const float* X   = (const float*)d_in[0];
  const float* Wx1 = (const float*)d_in[1];
  const float* Wh1 = (const float*)d_in[2];
  const float* bh1 = (const float*)d_in[3];
  const float* h01 = (const float*)d_in[4];
  const float* Wx2 = (const float*)d_in[5];
  const float* Wh2 = (const float*)d_in[6];
  const float* bh2 = (const float*)d_in[7];
  const float* h02 = (const float*)d_in[8];
  const float* Wl  = (const float*)d_in[9];
  const float* bl  = (const float*)d_in[10];
  float* out = (float*)d_out;

  // workspace layout: [flags1: 1KB][flags2: 1KB][pad][H1: 64MB][H2: 64MB]
  char* ws = (char*)d_ws;
  int*   flags1 = (int*)ws;
  int*   flags2 = (int*)(ws + 1024);
  float* H1 = (float*)(ws + 4096);
  float* H2 = H1 + (size_t)TT * MM;

  hipMemsetAsync(ws, 0xFF, 2048, stream);   // both flag arrays -> -1

  dim3 blk(256);

  // Xp1 = X @ Wx1 + bh1   (in-place scanned afterwards -> becomes H1)
  gemm_bias_f32<<<dim3(MM/128, TT/128), blk, 0, stream>>>(X, Wx1, bh1, H1, TT, MM, DD);

  { // scan layer 1 (cooperative: guarantees all 256 WGs co-resident)
    float* hx = H1; const float* wh = Wh1; const float* h0p = h01; int* fl = flags1;
    void* args[] = {&hx, &wh, &h0p, &fl};
    hipLaunchCooperativeKernel((const void*)rnn_scan_f32, dim3(SCAN_WGS), blk, args, 0, stream);
  }

  // Xp2 = H1 @ Wx2 + bh2
  gemm_bias_f32<<<dim3(MM/128, TT/128), blk, 0, stream>>>(H1, Wx2, bh2, H2, TT, MM, MM);

  { // scan layer 2
    float* hx = H2; const float* wh = Wh2; const float* h0p = h02; int* fl = flags2;
    void* args[] = {&hx, &wh, &h0p, &fl};
    hipLaunchCooperativeKernel((const void*)rnn_scan_f32, dim3(SCAN_WGS), blk, args, 0, stream);
  }

  // logits = H2 @ Wl + bl
  gemm_bias_f32<<<dim3(KK/128, TT/128), blk, 0, stream>>>(H2, Wl, bl, out, TT, KK, MM);
}

// Round 3
// 51132.761 us; speedup vs baseline: 1.6537x; 1.6537x over previous
//
#include <hip/hip_runtime.h>
#include <cstdint>
#include <cstddef>

#define TT 8192
#define DD 512
#define MM 2048   // M1 == M2
#define KK 1024
#define SCAN_WGS 256

typedef float f32x4 __attribute__((ext_vector_type(4)));
typedef int   i32x4 __attribute__((ext_vector_type(4)));

// ---------- coherent (L3 / coherence-point) memory helpers ----------
// sc0 sc1 bypasses L1+L2 on gfx950 -> reads/writes meet at the memory-side L3,
// which is the only cache level coherent across XCDs.
__device__ __forceinline__ void coh_load_i4x2(const int* p, i32x4& a, i32x4& b) {
  asm volatile("global_load_dwordx4 %0, %2, off sc0 sc1\n\t"
               "global_load_dwordx4 %1, %2, off offset:16 sc0 sc1\n\t"
               "s_waitcnt vmcnt(0)"
               : "=v"(a), "=v"(b) : "v"(p) : "memory");
}
__device__ __forceinline__ void coh_store_f4x2(float* p, f32x4 a, f32x4 b) {
  asm volatile("global_store_dwordx4 %0, %1, off sc0 sc1\n\t"
               "global_store_dwordx4 %0, %2, off offset:16 sc0 sc1"
               :: "v"(p), "v"(a), "v"(b) : "memory");
}

// ---------- fp32 tiled GEMM: C[M,N] = A[M,K] @ B[K,N] + bias[N] ----------
__global__ void __launch_bounds__(256) gemm_bias_f32(
    const float* __restrict__ A, const float* __restrict__ B,
    const float* __restrict__ bias, float* __restrict__ C,
    int M, int N, int K)
{
  __shared__ float As[16][128];   // As[k][m]
  __shared__ float Bs[16][128];   // Bs[k][n]
  const int tid = threadIdx.x;
  const int tx = tid & 15, ty = tid >> 4;
  const int row0 = blockIdx.y * 128, col0 = blockIdx.x * 128;
  const int arow = tid >> 1;          // 0..127
  const int ak0  = (tid & 1) * 8;     // 0 or 8
  const int brow = tid >> 4;          // 0..15
  const int bcol = (tid & 15) * 8;

  const float* Aptr = A + (size_t)(row0 + arow) * K + ak0;
  const float* Bptr = B + (size_t)brow * N + col0 + bcol;

  float acc[8][8];
  #pragma unroll
  for (int i = 0; i < 8; ++i)
    #pragma unroll
    for (int j = 0; j < 8; ++j) acc[i][j] = 0.f;

  for (int kk = 0; kk < K; kk += 16) {
    float4 a0 = *(const float4*)(Aptr + kk);
    float4 a1 = *(const float4*)(Aptr + kk + 4);
    float4 b0 = *(const float4*)(Bptr + (size_t)kk * N);
    float4 b1 = *(const float4*)(Bptr + (size_t)kk * N + 4);
    __syncthreads();
    As[ak0+0][arow] = a0.x; As[ak0+1][arow] = a0.y;
    As[ak0+2][arow] = a0.z; As[ak0+3][arow] = a0.w;
    As[ak0+4][arow] = a1.x; As[ak0+5][arow] = a1.y;
    As[ak0+6][arow] = a1.z; As[ak0+7][arow] = a1.w;
    *(float4*)&Bs[brow][bcol]     = b0;
    *(float4*)&Bs[brow][bcol + 4] = b1;
    __syncthreads();
    #pragma unroll
    for (int k = 0; k < 16; ++k) {
      float4 av0 = *(float4*)&As[k][ty*8];
      float4 av1 = *(float4*)&As[k][ty*8 + 4];
      float4 bv0 = *(float4*)&Bs[k][tx*4];
      float4 bv1 = *(float4*)&Bs[k][64 + tx*4];
      float ar[8] = {av0.x,av0.y,av0.z,av0.w,av1.x,av1.y,av1.z,av1.w};
      float br[8] = {bv0.x,bv0.y,bv0.z,bv0.w,bv1.x,bv1.y,bv1.z,bv1.w};
      #pragma unroll
      for (int i = 0; i < 8; ++i)
        #pragma unroll
        for (int j = 0; j < 8; ++j)
          acc[i][j] += ar[i] * br[j];
    }
  }

  float4 bi0 = *(const float4*)&bias[col0 + tx*4];
  float4 bi1 = *(const float4*)&bias[col0 + 64 + tx*4];
  #pragma unroll
  for (int i = 0; i < 8; ++i) {
    size_t r = (size_t)(row0 + ty*8 + i) * N;
    float4 o0 = make_float4(acc[i][0]+bi0.x, acc[i][1]+bi0.y, acc[i][2]+bi0.z, acc[i][3]+bi0.w);
    float4 o1 = make_float4(acc[i][4]+bi1.x, acc[i][5]+bi1.y, acc[i][6]+bi1.z, acc[i][7]+bi1.w);
    *(float4*)&C[r + col0 + tx*4]      = o0;
    *(float4*)&C[r + col0 + 64 + tx*4] = o1;
  }
}

// ---------- persistent RNN scan: H[t] = relu(Xp[t] + H[t-1] @ Wh) ----------
// 256 WGs x 256 threads. WG w owns output columns [8w, 8w+8).
// Wh column slice register-resident (64 VGPR/thread).
// NO flags: H is pre-memset to 0xFF (negative-NaN bit patterns). Outputs are
// post-ReLU (sign bit 0), so consumers poll the data itself via a sign-bit
// check -> single store->load hop per step on the critical path.
__global__ void __launch_bounds__(256, 1) rnn_scan_f32(
    const float* __restrict__ Xp, float* __restrict__ H,
    const float* __restrict__ Wh, const float* __restrict__ h0)
{
  __shared__ float h_s[MM];
  __shared__ float h_out[8];
  const int tid  = threadIdx.x;
  const int wg   = blockIdx.x;
  const int lane = tid & 63;
  const int wv   = tid >> 6;            // wave 0..3, owns cols wv*2, wv*2+1
  const int c0   = wg * 8 + wv * 2;

  // Weight slice in registers: w0[i],w1[i] = Wh[k][c0], Wh[k][c0+1],
  // k = lane*4 + 256*i + {0..3}
  float4 w0[8], w1[8];
  #pragma unroll
  for (int i = 0; i < 8; ++i) {
    const int kb = lane*4 + 256*i;
    float2 e0 = *(const float2*)&Wh[(size_t)(kb+0)*MM + c0];
    float2 e1 = *(const float2*)&Wh[(size_t)(kb+1)*MM + c0];
    float2 e2 = *(const float2*)&Wh[(size_t)(kb+2)*MM + c0];
    float2 e3 = *(const float2*)&Wh[(size_t)(kb+3)*MM + c0];
    w0[i] = make_float4(e0.x, e1.x, e2.x, e3.x);
    w1[i] = make_float4(e0.y, e1.y, e2.y, e3.y);
  }

  for (int t = 0; t < TT; ++t) {
    // ---- obtain h_{t-1} slice (8 floats, produced by WG tid) ----
    float4 ha, hb;
    if (t == 0) {
      ha = ((const float4*)h0)[tid*2];
      hb = ((const float4*)h0)[tid*2 + 1];
    } else {
      const int* src = (const int*)(H + (size_t)(t-1)*MM + tid*8);
      i32x4 a, b;
      do {
        coh_load_i4x2(src, a, b);
      } while ((a.x | a.y | a.z | a.w | b.x | b.y | b.z | b.w) < 0);
      ha = make_float4(__int_as_float(a.x), __int_as_float(a.y),
                       __int_as_float(a.z), __int_as_float(a.w));
      hb = make_float4(__int_as_float(b.x), __int_as_float(b.y),
                       __int_as_float(b.z), __int_as_float(b.w));
    }
    ((float4*)h_s)[tid*2]     = ha;
    ((float4*)h_s)[tid*2 + 1] = hb;
    __syncthreads();

    // x_t for my columns (plain cached load; Xp is read-only here)
    float xv = 0.f;
    if (lane < 2) xv = Xp[(size_t)t*MM + c0 + lane];

    // ---- dot products over k, weights register-resident ----
    float s0 = 0.f, s1 = 0.f;
    #pragma unroll
    for (int i = 0; i < 8; ++i) {
      float4 h4 = *(float4*)&h_s[lane*4 + 256*i];
      s0 += h4.x*w0[i].x + h4.y*w0[i].y + h4.z*w0[i].z + h4.w*w0[i].w;
      s1 += h4.x*w1[i].x + h4.y*w1[i].y + h4.z*w1[i].z + h4.w*w1[i].w;
    }
    #pragma unroll
    for (int off = 32; off; off >>= 1) {
      s0 += __shfl_xor(s0, off);
      s1 += __shfl_xor(s1, off);
    }
    if (lane < 2) {
      float s = (lane == 0) ? s0 : s1;
      h_out[wv*2 + lane] = fmaxf(xv + s, 0.f);
    }
    __syncthreads();

    // ---- publish: one thread, two 16B coherent stores (single hop) ----
    if (tid == 0) {
      f32x4 o0 = *(f32x4*)&h_out[0];
      f32x4 o1 = *(f32x4*)&h_out[4];
      coh_store_f4x2(H + (size_t)t*MM + wg*8, o0, o1);
    }
  }
}

extern "C" void kernel_launch(void* const* d_in, const int* in_sizes, int n_in,
                              void* d_out, int out_size, void* d_ws, size_t ws_size,
                              hipStream_t stream) {
  (void)in_sizes; (void)n_in; (void)out_size; (void)ws_size;

  const float* X   = (const float*)d_in[0];
  const float* Wx1 = (const float*)d_in[1];
  const float* Wh1 = (const float*)d_in[2];
  const float* bh1 = (const float*)d_in[3];
  const float* h01 = (const float*)d_in[4];
  const float* Wx2 = (const float*)d_in[5];
  const float* Wh2 = (const float*)d_in[6];
  const float* bh2 = (const float*)d_in[7];
  const float* h02 = (const float*)d_in[8];
  const float* Wl  = (const float*)d_in[9];
  const float* bl  = (const float*)d_in[10];
  float* out = (float*)d_out;

  // workspace: [bufA: 64MB (Xp1/Xp2)] [bufB: 64MB (H1/H2, sentinel-polled)]
  const size_t NBUF = (size_t)TT * MM;
  float* bufA = (float*)d_ws;
  float* bufB = bufA + NBUF;

  dim3 blk(256);

  // sentinel-init H1 (0xFF = negative NaN bit patterns, sign bit set)
  (void)hipMemsetAsync(bufB, 0xFF, NBUF * sizeof(float), stream);

  // Xp1 = X @ Wx1 + bh1
  gemm_bias_f32<<<dim3(MM/128, TT/128), blk, 0, stream>>>(X, Wx1, bh1, bufA, TT, MM, DD);

  { // scan layer 1: bufA (Xp1) -> bufB (H1)
    const float* xp = bufA; float* h = bufB; const float* wh = Wh1; const float* h0p = h01;
    void* args[] = {&xp, &h, &wh, &h0p};
    (void)hipLaunchCooperativeKernel((const void*)rnn_scan_f32, dim3(SCAN_WGS), blk, args, 0, stream);
  }

  // Xp2 = H1 @ Wx2 + bh2   (bufB -> bufA; Xp1 is dead)
  gemm_bias_f32<<<dim3(MM/128, TT/128), blk, 0, stream>>>(bufB, Wx2, bh2, bufA, TT, MM, MM);

  // re-sentinel bufB for H2 (after GEMM2 consumed H1)
  (void)hipMemsetAsync(bufB, 0xFF, NBUF * sizeof(float), stream);

  { // scan layer 2: bufA (Xp2) -> bufB (H2)
    const float* xp = bufA; float* h = bufB; const float* wh = Wh2; const float* h0p = h02;
    void* args[] = {&xp, &h, &wh, &h0p};
    (void)hipLaunchCooperativeKernel((const void*)rnn_scan_f32, dim3(SCAN_WGS), blk, args, 0, stream);
  }

  // logits = H2 @ Wl + bl
  gemm_bias_f32<<<dim3(KK/128, TT/128), blk, 0, stream>>>(bufB, Wl, bl, out, TT, KK, MM);
}